// Round 1
// baseline (377.283 us; speedup 1.0000x reference)
//
#include <hip/hip_runtime.h>
#include <math.h>

typedef __bf16 bf16x8 __attribute__((ext_vector_type(8)));
typedef float f32x4 __attribute__((ext_vector_type(4)));

// ---------- helpers ----------

__device__ __forceinline__ unsigned short f2bf(float f) {
    unsigned int u = __float_as_uint(f);
    u += 0x7FFFu + ((u >> 16) & 1u);   // round-to-nearest-even
    return (unsigned short)(u >> 16);
}

__device__ __forceinline__ float logcosh1(float v) {
    float a = fabsf(v);
    return a + log1pf(__expf(-2.0f * a)) - 0.6931471805599453f;
}

__device__ __forceinline__ void gload_lds16(const void* g, void* l) {
    __builtin_amdgcn_global_load_lds(
        (__attribute__((address_space(1))) void*)(void*)g,
        (__attribute__((address_space(3))) void*)l, 16, 0, 0);
}

// ---------- kernel 1: invert permutations ----------
// inv[g][perm[g][n]] = n
__global__ __launch_bounds__(256) void k_invert(const int* __restrict__ perms,
                                                int* __restrict__ inv) {
    int t = blockIdx.x * 256 + threadIdx.x;
    int g = t >> 10, n = t & 1023;
    inv[(g << 10) + perms[t]] = n;
}

// ---------- kernel 2: bT[j][k] = bf16(W[inv[g][k]][f]), j = g*16+f ----------
__global__ __launch_bounds__(256) void k_build_bt(const float* __restrict__ W,
                                                  const int* __restrict__ inv,
                                                  unsigned short* __restrict__ bT) {
    int j = blockIdx.x;
    int g = j >> 4, f = j & 15;
    const int* invg = inv + (g << 10);
    size_t rowbase = (size_t)j << 10;
#pragma unroll
    for (int i = 0; i < 4; ++i) {
        int k = (i << 8) + threadIdx.x;
        int n = invg[k];
        bT[rowbase + k] = f2bf(W[(n << 4) + f]);
    }
}

// ---------- kernel 3: x -> bf16, out[row] = v_bias * sum(x[row]) ----------
__global__ __launch_bounds__(256) void k_convert(const float* __restrict__ x,
                                                 const float* __restrict__ vb,
                                                 unsigned short* __restrict__ xb,
                                                 float* __restrict__ out) {
    int row = blockIdx.x, tid = threadIdx.x;
    size_t base = ((size_t)row << 10) + (tid << 2);
    float4 v = *reinterpret_cast<const float4*>(x + base);
    ushort4 h;
    h.x = f2bf(v.x); h.y = f2bf(v.y); h.z = f2bf(v.z); h.w = f2bf(v.w);
    *reinterpret_cast<ushort4*>(xb + base) = h;
    float s = v.x + v.y + v.z + v.w;
#pragma unroll
    for (int off = 32; off > 0; off >>= 1) s += __shfl_down(s, off);
    __shared__ float ls[4];
    if ((tid & 63) == 0) ls[tid >> 6] = s;
    __syncthreads();
    if (tid == 0) out[row] = vb[0] * (ls[0] + ls[1] + ls[2] + ls[3]);
}

// ---------- kernel 4: GEMM + fused logcosh + row-reduce ----------
// C[row, j] = sum_k xb[row,k] * bT[j,k];  partial[cb][row] = sum_{j in colblock} logcosh(C+bias)
// 128x128 tile, BK=64, 4 waves (2x2 of 64x64), mfma_f32_16x16x32_bf16.
// LDS tiles [128][64] bf16 with XOR chunk swizzle (chunk 16B, pos = c ^ (row&7)),
// staged via global_load_lds(16B) with pre-swizzled global source (linear LDS dest).
__global__ __launch_bounds__(256) void k_gemm(const unsigned short* __restrict__ xb,
                                              const unsigned short* __restrict__ bT,
                                              const float* __restrict__ bias,
                                              float* __restrict__ partial, int B) {
    __shared__ unsigned short As[128 * 64];
    __shared__ unsigned short Bs[128 * 64];
    __shared__ float rowsum2[2][128];

    const int tid = threadIdx.x;
    const int lane = tid & 63;
    const int wv = tid >> 6;
    const int wrow = wv >> 1, wcol = wv & 1;
    const int cbx = blockIdx.x;        // col block (0..31)
    const int row0 = blockIdx.y << 7;  // row block * 128
    const int j0 = cbx << 7;

    const int lr = lane & 15;   // row-within-16 for A/B frags; col for C/D
    const int lk = lane >> 4;   // k-octet selector / C row group

    f32x4 acc[4][4];
#pragma unroll
    for (int m = 0; m < 4; ++m)
#pragma unroll
        for (int n = 0; n < 4; ++n)
            acc[m][n] = {0.f, 0.f, 0.f, 0.f};

    for (int kt = 0; kt < 1024; kt += 64) {
        // stage A tile: 128 rows x 64 cols bf16 = 1024 chunks of 16B
#pragma unroll
        for (int i = 0; i < 4; ++i) {
            int c0 = i * 256 + wv * 64;          // wave-uniform chunk base
            int chunk = c0 + lane;
            int r = chunk >> 3;
            int cs = (chunk & 7) ^ (r & 7);      // pre-swizzled source octet
            gload_lds16(xb + (((size_t)(row0 + r)) << 10) + kt + (cs << 3),
                        As + (c0 << 3));
        }
        // stage B tile (bT rows j0..j0+127)
#pragma unroll
        for (int i = 0; i < 4; ++i) {
            int c0 = i * 256 + wv * 64;
            int chunk = c0 + lane;
            int r = chunk >> 3;
            int cs = (chunk & 7) ^ (r & 7);
            gload_lds16(bT + (((size_t)(j0 + r)) << 10) + kt + (cs << 3),
                        Bs + (c0 << 3));
        }
        __syncthreads();

#pragma unroll
        for (int kk = 0; kk < 2; ++kk) {
            bf16x8 aF[4], bF[4];
#pragma unroll
            for (int m = 0; m < 4; ++m) {
                int r = (wrow << 6) + (m << 4) + lr;
                int pos = ((kk << 2) + lk) ^ (r & 7);
                aF[m] = *reinterpret_cast<const bf16x8*>(As + (r << 6) + (pos << 3));
            }
#pragma unroll
            for (int n = 0; n < 4; ++n) {
                int r = (wcol << 6) + (n << 4) + lr;
                int pos = ((kk << 2) + lk) ^ (r & 7);
                bF[n] = *reinterpret_cast<const bf16x8*>(Bs + (r << 6) + (pos << 3));
            }
#pragma unroll
            for (int m = 0; m < 4; ++m)
#pragma unroll
                for (int n = 0; n < 4; ++n)
                    acc[m][n] = __builtin_amdgcn_mfma_f32_16x16x32_bf16(
                        aF[m], bF[n], acc[m][n], 0, 0, 0);
        }
        __syncthreads();
    }

    // epilogue: logcosh + reduce over this block's 128 columns
    const float bv = bias[lr];  // col % 16 == lane&15
#pragma unroll
    for (int m = 0; m < 4; ++m) {
#pragma unroll
        for (int r = 0; r < 4; ++r) {
            float s = 0.f;
#pragma unroll
            for (int n = 0; n < 4; ++n) s += logcosh1(acc[m][n][r] + bv);
            // reduce across the 16 lanes holding the same row (cols differ)
            s += __shfl_xor(s, 1);
            s += __shfl_xor(s, 2);
            s += __shfl_xor(s, 4);
            s += __shfl_xor(s, 8);
            if (lr == 0)
                rowsum2[wcol][(wrow << 6) + (m << 4) + (lk << 2) + r] = s;
        }
    }
    __syncthreads();
    if (tid < 128)
        partial[(size_t)cbx * B + row0 + tid] = rowsum2[0][tid] + rowsum2[1][tid];
}

// ---------- kernel 5: out[b] += sum_cb partial[cb][b] ----------
__global__ __launch_bounds__(256) void k_final(const float* __restrict__ partial,
                                               float* __restrict__ out, int ncb, int B) {
    int b = blockIdx.x * 256 + threadIdx.x;
    float s = out[b];
    for (int c = 0; c < ncb; ++c) s += partial[(size_t)c * B + b];
    out[b] = s;
}

// ---------- launch ----------
extern "C" void kernel_launch(void* const* d_in, const int* in_sizes, int n_in,
                              void* d_out, int out_size, void* d_ws, size_t ws_size,
                              hipStream_t stream) {
    const float* x      = (const float*)d_in[0];  // [B,1024]
    const float* W      = (const float*)d_in[1];  // [1024,16]
    const float* bias   = (const float*)d_in[2];  // [16]
    const float* v_bias = (const float*)d_in[3];  // [1]
    const int*   perms  = (const int*)d_in[4];    // [G,1024]
    float* out = (float*)d_out;

    const int N  = 1024;
    const int B  = in_sizes[0] / N;   // 16384
    const int G  = in_sizes[4] / N;   // 256
    const int GF = G * 16;            // 4096
    const int NCB = GF / 128;         // 32 col blocks

    char* w = (char*)d_ws;
    unsigned short* xb = (unsigned short*)w;                           // B*N*2   = 32 MB
    unsigned short* bT = (unsigned short*)(w + (size_t)B * N * 2);     // GF*N*2  = 8 MB
    int* inv = (int*)(w + (size_t)B * N * 2 + (size_t)GF * N * 2);     // G*N*4   = 1 MB
    float* partial = (float*)(w + (size_t)B * N * 2 + (size_t)GF * N * 2
                              + (size_t)G * N * 4);                    // NCB*B*4 = 2 MB

    k_invert<<<G * N / 256, 256, 0, stream>>>(perms, inv);
    k_build_bt<<<GF, 256, 0, stream>>>(W, inv, bT);
    k_convert<<<B, 256, 0, stream>>>(x, v_bias, xb, out);
    k_gemm<<<dim3(NCB, B / 128), 256, 0, stream>>>(xb, bT, bias, partial, B);
    k_final<<<B / 256, 256, 0, stream>>>(partial, out, NCB, B);
}

// Round 2
// 223.987 us; speedup vs baseline: 1.6844x; 1.6844x over previous
//
#include <hip/hip_runtime.h>
#include <math.h>

typedef __bf16 bf16x8 __attribute__((ext_vector_type(8)));
typedef float f32x4 __attribute__((ext_vector_type(4)));

// ---------- helpers ----------

__device__ __forceinline__ unsigned short f2bf(float f) {
    unsigned int u = __float_as_uint(f);
    u += 0x7FFFu + ((u >> 16) & 1u);   // round-to-nearest-even
    return (unsigned short)(u >> 16);
}

// fast logcosh: a + log(1+exp(-2a)) - log2, using HW v_exp/v_log.
// abs err ~1e-6 per element (budget is ~0.02/element) — TRANS pipe, not VALU.
__device__ __forceinline__ float logcosh_fast(float v) {
    float a = fabsf(v);
    float t = __expf(-2.0f * a);           // v_exp_f32 (+1 mul)
    return a + (__logf(1.0f + t) - 0.6931471805599453f);  // v_log_f32 (+mul,+add)
}

// DPP row_shr add: after shr 1,2,4,8 lane 15 of each 16-lane row holds the row sum.
template <int CTRL>
__device__ __forceinline__ float dppadd(float x) {
    int y = __builtin_amdgcn_update_dpp(0, __float_as_int(x), CTRL, 0xf, 0xf, true);
    return x + __int_as_float(y);
}

__device__ __forceinline__ void gload_lds16(const void* g, void* l) {
    __builtin_amdgcn_global_load_lds(
        (__attribute__((address_space(1))) void*)(void*)g,
        (__attribute__((address_space(3))) void*)l, 16, 0, 0);
}

// ---------- kernel 1: invert permutations ----------
__global__ __launch_bounds__(256) void k_invert(const int* __restrict__ perms,
                                                int* __restrict__ inv) {
    int t = blockIdx.x * 256 + threadIdx.x;
    int g = t >> 10, n = t & 1023;
    inv[(g << 10) + perms[t]] = n;
}

// ---------- kernel 2: bT[j][k] = bf16(W[inv[g][k]][f]), j = g*16+f ----------
__global__ __launch_bounds__(256) void k_build_bt(const float* __restrict__ W,
                                                  const int* __restrict__ inv,
                                                  unsigned short* __restrict__ bT) {
    int j = blockIdx.x;
    int g = j >> 4, f = j & 15;
    const int* invg = inv + (g << 10);
    size_t rowbase = (size_t)j << 10;
#pragma unroll
    for (int i = 0; i < 4; ++i) {
        int k = (i << 8) + threadIdx.x;
        int n = invg[k];
        bT[rowbase + k] = f2bf(W[(n << 4) + f]);
    }
}

// ---------- kernel 3: x -> bf16, out[row] = v_bias * sum(x[row]) ----------
__global__ __launch_bounds__(256) void k_convert(const float* __restrict__ x,
                                                 const float* __restrict__ vb,
                                                 unsigned short* __restrict__ xb,
                                                 float* __restrict__ out) {
    int row = blockIdx.x, tid = threadIdx.x;
    size_t base = ((size_t)row << 10) + (tid << 2);
    float4 v = *reinterpret_cast<const float4*>(x + base);
    ushort4 h;
    h.x = f2bf(v.x); h.y = f2bf(v.y); h.z = f2bf(v.z); h.w = f2bf(v.w);
    *reinterpret_cast<ushort4*>(xb + base) = h;
    float s = v.x + v.y + v.z + v.w;
#pragma unroll
    for (int off = 32; off > 0; off >>= 1) s += __shfl_down(s, off);
    __shared__ float ls[4];
    if ((tid & 63) == 0) ls[tid >> 6] = s;
    __syncthreads();
    if (tid == 0) out[row] = vb[0] * (ls[0] + ls[1] + ls[2] + ls[3]);
}

// ---------- kernel 4: GEMM + fused logcosh + row-reduce ----------
__global__ __launch_bounds__(256) void k_gemm(const unsigned short* __restrict__ xb,
                                              const unsigned short* __restrict__ bT,
                                              const float* __restrict__ bias,
                                              float* __restrict__ partial, int B) {
    __shared__ unsigned short As[128 * 64];
    __shared__ unsigned short Bs[128 * 64];
    __shared__ float rowsum2[2][128];

    const int tid = threadIdx.x;
    const int lane = tid & 63;
    const int wv = tid >> 6;
    const int wrow = wv >> 1, wcol = wv & 1;
    const int cbx = blockIdx.x;        // col block (0..31)
    const int row0 = blockIdx.y << 7;  // row block * 128
    const int j0 = cbx << 7;

    const int lr = lane & 15;   // row-within-16 for A/B frags; col for C/D
    const int lk = lane >> 4;   // k-octet selector / C row group

    f32x4 acc[4][4];
#pragma unroll
    for (int m = 0; m < 4; ++m)
#pragma unroll
        for (int n = 0; n < 4; ++n)
            acc[m][n] = {0.f, 0.f, 0.f, 0.f};

    for (int kt = 0; kt < 1024; kt += 64) {
        // stage A tile: 128 rows x 64 cols bf16 = 1024 chunks of 16B
#pragma unroll
        for (int i = 0; i < 4; ++i) {
            int c0 = i * 256 + wv * 64;          // wave-uniform chunk base
            int chunk = c0 + lane;
            int r = chunk >> 3;
            int cs = (chunk & 7) ^ (r & 7);      // pre-swizzled source octet
            gload_lds16(xb + (((size_t)(row0 + r)) << 10) + kt + (cs << 3),
                        As + (c0 << 3));
        }
        // stage B tile (bT rows j0..j0+127)
#pragma unroll
        for (int i = 0; i < 4; ++i) {
            int c0 = i * 256 + wv * 64;
            int chunk = c0 + lane;
            int r = chunk >> 3;
            int cs = (chunk & 7) ^ (r & 7);
            gload_lds16(bT + (((size_t)(j0 + r)) << 10) + kt + (cs << 3),
                        Bs + (c0 << 3));
        }
        __syncthreads();

#pragma unroll
        for (int kk = 0; kk < 2; ++kk) {
            bf16x8 aF[4], bF[4];
#pragma unroll
            for (int m = 0; m < 4; ++m) {
                int r = (wrow << 6) + (m << 4) + lr;
                int pos = ((kk << 2) + lk) ^ (r & 7);
                aF[m] = *reinterpret_cast<const bf16x8*>(As + (r << 6) + (pos << 3));
            }
#pragma unroll
            for (int n = 0; n < 4; ++n) {
                int r = (wcol << 6) + (n << 4) + lr;
                int pos = ((kk << 2) + lk) ^ (r & 7);
                bF[n] = *reinterpret_cast<const bf16x8*>(Bs + (r << 6) + (pos << 3));
            }
#pragma unroll
            for (int m = 0; m < 4; ++m)
#pragma unroll
                for (int n = 0; n < 4; ++n)
                    acc[m][n] = __builtin_amdgcn_mfma_f32_16x16x32_bf16(
                        aF[m], bF[n], acc[m][n], 0, 0, 0);
        }
        __syncthreads();
    }

    // epilogue: fast logcosh + DPP row-reduce over this block's 128 columns
    const float bv = bias[lr];  // col % 16 == lane&15
#pragma unroll
    for (int m = 0; m < 4; ++m) {
#pragma unroll
        for (int r = 0; r < 4; ++r) {
            float s = 0.f;
#pragma unroll
            for (int n = 0; n < 4; ++n) s += logcosh_fast(acc[m][n][r] + bv);
            // reduce across the 16 lanes holding the same row (pure-VALU DPP)
            s = dppadd<0x111>(s);   // row_shr:1
            s = dppadd<0x112>(s);   // row_shr:2
            s = dppadd<0x114>(s);   // row_shr:4
            s = dppadd<0x118>(s);   // row_shr:8
            if (lr == 15)
                rowsum2[wcol][(wrow << 6) + (m << 4) + (lk << 2) + r] = s;
        }
    }
    __syncthreads();
    if (tid < 128)
        partial[(size_t)cbx * B + row0 + tid] = rowsum2[0][tid] + rowsum2[1][tid];
}

// ---------- kernel 5: out[b] += sum_cb partial[cb][b] ----------
__global__ __launch_bounds__(256) void k_final(const float* __restrict__ partial,
                                               float* __restrict__ out, int ncb, int B) {
    int b = blockIdx.x * 256 + threadIdx.x;
    float s = out[b];
    for (int c = 0; c < ncb; ++c) s += partial[(size_t)c * B + b];
    out[b] = s;
}

// ---------- launch ----------
extern "C" void kernel_launch(void* const* d_in, const int* in_sizes, int n_in,
                              void* d_out, int out_size, void* d_ws, size_t ws_size,
                              hipStream_t stream) {
    const float* x      = (const float*)d_in[0];  // [B,1024]
    const float* W      = (const float*)d_in[1];  // [1024,16]
    const float* bias   = (const float*)d_in[2];  // [16]
    const float* v_bias = (const float*)d_in[3];  // [1]
    const int*   perms  = (const int*)d_in[4];    // [G,1024]
    float* out = (float*)d_out;

    const int N  = 1024;
    const int B  = in_sizes[0] / N;   // 16384
    const int G  = in_sizes[4] / N;   // 256
    const int GF = G * 16;            // 4096
    const int NCB = GF / 128;         // 32 col blocks

    char* w = (char*)d_ws;
    unsigned short* xb = (unsigned short*)w;                           // B*N*2   = 32 MB
    unsigned short* bT = (unsigned short*)(w + (size_t)B * N * 2);     // GF*N*2  = 8 MB
    int* inv = (int*)(w + (size_t)B * N * 2 + (size_t)GF * N * 2);     // G*N*4   = 1 MB
    float* partial = (float*)(w + (size_t)B * N * 2 + (size_t)GF * N * 2
                              + (size_t)G * N * 4);                    // NCB*B*4 = 2 MB

    k_invert<<<G * N / 256, 256, 0, stream>>>(perms, inv);
    k_build_bt<<<GF, 256, 0, stream>>>(W, inv, bT);
    k_convert<<<B, 256, 0, stream>>>(x, v_bias, xb, out);
    k_gemm<<<dim3(NCB, B / 128), 256, 0, stream>>>(xb, bT, bias, partial, B);
    k_final<<<B / 256, 256, 0, stream>>>(partial, out, NCB, B);
}

// Round 3
// 196.686 us; speedup vs baseline: 1.9182x; 1.1388x over previous
//
#include <hip/hip_runtime.h>
#include <math.h>

typedef __bf16 bf16x8 __attribute__((ext_vector_type(8)));
typedef float f32x4 __attribute__((ext_vector_type(4)));

// ---------- helpers ----------

__device__ __forceinline__ unsigned short f2bf(float f) {
    unsigned int u = __float_as_uint(f);
    u += 0x7FFFu + ((u >> 16) & 1u);   // round-to-nearest-even
    return (unsigned short)(u >> 16);
}

// fast logcosh via HW v_exp/v_log (TRANS pipe). abs err ~1e-6/elem, budget 0.02.
__device__ __forceinline__ float logcosh_fast(float v) {
    float a = fabsf(v);
    float t = __expf(-2.0f * a);
    return a + (__logf(1.0f + t) - 0.6931471805599453f);
}

// DPP row_shr add; after shr 1,2,4,8 lane 15 of each 16-lane row holds row sum.
template <int CTRL>
__device__ __forceinline__ float dppadd(float x) {
    int y = __builtin_amdgcn_update_dpp(0, __float_as_int(x), CTRL, 0xf, 0xf, true);
    return x + __int_as_float(y);
}

__device__ __forceinline__ void gload_lds16(const void* g, void* l) {
    __builtin_amdgcn_global_load_lds(
        (__attribute__((address_space(1))) void*)(void*)g,
        (__attribute__((address_space(3))) void*)l, 16, 0, 0);
}

// ---------- kernel 1: invert permutations ----------
__global__ __launch_bounds__(256) void k_invert(const int* __restrict__ perms,
                                                int* __restrict__ inv) {
    int t = blockIdx.x * 256 + threadIdx.x;
    int g = t >> 10, n = t & 1023;
    inv[(g << 10) + perms[t]] = n;
}

// ---------- kernel 2: bT[j][k] = bf16(W[inv[g][k]][f]), j = g*16+f ----------
__global__ __launch_bounds__(256) void k_build_bt(const float* __restrict__ W,
                                                  const int* __restrict__ inv,
                                                  unsigned short* __restrict__ bT) {
    int j = blockIdx.x;
    int g = j >> 4, f = j & 15;
    const int* invg = inv + (g << 10);
    size_t rowbase = (size_t)j << 10;
#pragma unroll
    for (int i = 0; i < 4; ++i) {
        int k = (i << 8) + threadIdx.x;
        int n = invg[k];
        bT[rowbase + k] = f2bf(W[(n << 4) + f]);
    }
}

// ---------- kernel 3: x -> bf16, out[row] = v_bias * sum(x[row]) ----------
__global__ __launch_bounds__(256) void k_convert(const float* __restrict__ x,
                                                 const float* __restrict__ vb,
                                                 unsigned short* __restrict__ xb,
                                                 float* __restrict__ out) {
    int row = blockIdx.x, tid = threadIdx.x;
    size_t base = ((size_t)row << 10) + (tid << 2);
    float4 v = *reinterpret_cast<const float4*>(x + base);
    ushort4 h;
    h.x = f2bf(v.x); h.y = f2bf(v.y); h.z = f2bf(v.z); h.w = f2bf(v.w);
    *reinterpret_cast<ushort4*>(xb + base) = h;
    float s = v.x + v.y + v.z + v.w;
#pragma unroll
    for (int off = 32; off > 0; off >>= 1) s += __shfl_down(s, off);
    __shared__ float ls[4];
    if ((tid & 63) == 0) ls[tid >> 6] = s;
    __syncthreads();
    if (tid == 0) out[row] = vb[0] * (ls[0] + ls[1] + ls[2] + ls[3]);
}

// ---------- kernel 4: 256x256 8-phase GEMM + fused logcosh + row-reduce ----------
// C[row, j] = sum_k xb[row,k] * bT[j,k]; 16 K-tiles of BK=64, double-buffered LDS,
// counted vmcnt (never 0 in steady state), front-loaded ds_reads (race-safe),
// setprio around MFMA clusters, XCD-bijective block swizzle.

#define MFMA_QUAD(MH, NH)                                                        \
    _Pragma("unroll") for (int m_ = 0; m_ < 4; ++m_)                             \
    _Pragma("unroll") for (int n_ = 0; n_ < 2; ++n_)                             \
    _Pragma("unroll") for (int kk_ = 0; kk_ < 2; ++kk_)                          \
        acc[(MH) * 4 + m_][(NH) * 2 + n_] =                                      \
            __builtin_amdgcn_mfma_f32_16x16x32_bf16(                             \
                aF[(MH) * 4 + m_][kk_], bF[(NH) * 2 + n_][kk_],                  \
                acc[(MH) * 4 + m_][(NH) * 2 + n_], 0, 0, 0);

__global__ __launch_bounds__(512) void k_gemm(const unsigned short* __restrict__ xb,
                                              const unsigned short* __restrict__ bT,
                                              const float* __restrict__ bias,
                                              float* __restrict__ partial, int B) {
    __shared__ unsigned short As[2][256 * 64];
    __shared__ unsigned short Bs[2][256 * 64];

    const int tid = threadIdx.x;
    const int lane = tid & 63;
    const int wv = tid >> 6;           // 0..7
    const int wm = wv >> 2;            // 0..1  (M half)
    const int wn = wv & 3;             // 0..3  (N quarter)
    const int lr = lane & 15;
    const int lk = lane >> 4;

    // XCD-bijective swizzle (nwg = 1024, % 8 == 0)
    const int fid = blockIdx.y * gridDim.x + blockIdx.x;
    const int cpx = (gridDim.x * gridDim.y) >> 3;
    const int swz = (fid & 7) * cpx + (fid >> 3);
    const int cbx = swz & 15;          // col block (0..15)
    const int row0 = (swz >> 4) << 8;  // row block * 256
    const int j0 = cbx << 8;

    const unsigned short* xbase = xb + ((size_t)row0 << 10);
    const unsigned short* bbase = bT + ((size_t)j0 << 10);

    // stage one half-tile (128 rows x 64 cols bf16 = 16KB) = 2 gload_lds x 512 thr
    auto stage_half = [&](unsigned short* dst, const unsigned short* src, int h) {
#pragma unroll
        for (int j = 0; j < 2; ++j) {
            int c0 = (h * 128 + j * 64) * 8;       // base chunk of this instr
            int cc = c0 + tid;                     // this thread's 16B chunk
            int r = cc >> 3;                       // tile row 0..255
            int cs = (cc & 7) ^ (r & 7);           // pre-swizzled source octet
            gload_lds16(src + (((size_t)r) << 10) + (cs << 3),
                        dst + ((c0 + wv * 64) << 3));
        }
    };
    // per-window stage sequence: s0=(t+1,B,h1)  s1=(t+2,A,h0)  s2=(t+2,A,h1)  s3=(t+2,B,h0)
    auto stage_s = [&](int t, int s) {
        int tt = (s == 0) ? t + 1 : t + 2;
        if (tt >= 16) return;
        int p = tt & 1;
        int kt = tt << 6;
        if (s == 0)      stage_half(Bs[p], bbase + kt, 1);
        else if (s == 1) stage_half(As[p], xbase + kt, 0);
        else if (s == 2) stage_half(As[p], xbase + kt, 1);
        else             stage_half(Bs[p], bbase + kt, 0);
    };

    f32x4 acc[8][4];
#pragma unroll
    for (int m = 0; m < 8; ++m)
#pragma unroll
        for (int n = 0; n < 4; ++n)
            acc[m][n] = {0.f, 0.f, 0.f, 0.f};

    // ---- prologue: tile0 complete (4 halves), tile1 A0,A1,B0 ----
    stage_half(As[0], xbase + 0, 0);
    stage_half(As[0], xbase + 0, 1);
    stage_half(Bs[0], bbase + 0, 0);
    stage_half(Bs[0], bbase + 0, 1);
    stage_half(As[1], xbase + 64, 0);
    stage_half(As[1], xbase + 64, 1);
    stage_half(Bs[1], bbase + 64, 0);
    asm volatile("s_waitcnt vmcnt(6)" ::: "memory");   // tile0 landed; tile1's 6 in flight
    __builtin_amdgcn_s_barrier();

    // ---- main loop: one 4-phase window per K-tile ----
#pragma unroll 2
    for (int t = 0; t < 16; ++t) {
        const int p = t & 1;
        const unsigned short* Ap = As[p];
        const unsigned short* Bp = Bs[p];
        bf16x8 aF[8][2], bF[4][2];

        // ---- phase 1: front-load ALL frags of tile t, stage s0, MFMA q(0,0)
        __builtin_amdgcn_sched_barrier(0);
#pragma unroll
        for (int m = 0; m < 8; ++m) {
            int r = wm * 128 + m * 16 + lr;
#pragma unroll
            for (int kk = 0; kk < 2; ++kk) {
                int pos = ((kk << 2) + lk) ^ (r & 7);
                aF[m][kk] = *reinterpret_cast<const bf16x8*>(Ap + (r << 6) + (pos << 3));
            }
        }
#pragma unroll
        for (int n = 0; n < 4; ++n) {
            int rb = wn * 64 + n * 16 + lr;
#pragma unroll
            for (int kk = 0; kk < 2; ++kk) {
                int pos = ((kk << 2) + lk) ^ (rb & 7);
                bF[n][kk] = *reinterpret_cast<const bf16x8*>(Bp + (rb << 6) + (pos << 3));
            }
        }
        stage_s(t, 0);
        // all LDS reads of this buffer complete BEFORE the phase-1 barrier:
        // later stages into this buffer (phases 2-4, next window) cannot race them.
        asm volatile("s_waitcnt lgkmcnt(0)" ::: "memory");
        __builtin_amdgcn_sched_barrier(0);
        __builtin_amdgcn_s_setprio(1);
        MFMA_QUAD(0, 0)
        __builtin_amdgcn_s_setprio(0);
        __builtin_amdgcn_s_barrier();

        // ---- phase 2
        __builtin_amdgcn_sched_barrier(0);
        stage_s(t, 1);
        __builtin_amdgcn_s_barrier();
        __builtin_amdgcn_sched_barrier(0);
        __builtin_amdgcn_s_setprio(1);
        MFMA_QUAD(1, 0)
        __builtin_amdgcn_s_setprio(0);
        __builtin_amdgcn_s_barrier();

        // ---- phase 3
        __builtin_amdgcn_sched_barrier(0);
        stage_s(t, 2);
        __builtin_amdgcn_s_barrier();
        __builtin_amdgcn_sched_barrier(0);
        __builtin_amdgcn_s_setprio(1);
        MFMA_QUAD(0, 1)
        __builtin_amdgcn_s_setprio(0);
        __builtin_amdgcn_s_barrier();

        // ---- phase 4 (+ counted vmcnt: tile t+1 landed, 3 half-tiles in flight)
        __builtin_amdgcn_sched_barrier(0);
        stage_s(t, 3);
        __builtin_amdgcn_s_barrier();
        __builtin_amdgcn_sched_barrier(0);
        __builtin_amdgcn_s_setprio(1);
        MFMA_QUAD(1, 1)
        __builtin_amdgcn_s_setprio(0);
        if (t < 14) {
            asm volatile("s_waitcnt vmcnt(6)" ::: "memory");
        } else if (t == 14) {
            asm volatile("s_waitcnt vmcnt(0)" ::: "memory");
        }
        __builtin_amdgcn_s_barrier();
    }

    // ---- epilogue: fast logcosh + DPP row-reduce; reuse As as scratch ----
    float* rowsum = (float*)&As[0][0];   // [4][256]
    const float bv = bias[lr];           // C col % 16 == lane&15
#pragma unroll
    for (int m = 0; m < 8; ++m) {
#pragma unroll
        for (int r = 0; r < 4; ++r) {
            float s = 0.f;
#pragma unroll
            for (int n = 0; n < 4; ++n) s += logcosh_fast(acc[m][n][r] + bv);
            s = dppadd<0x111>(s);
            s = dppadd<0x112>(s);
            s = dppadd<0x114>(s);
            s = dppadd<0x118>(s);
            if (lr == 15)
                rowsum[wn * 256 + wm * 128 + m * 16 + lk * 4 + r] = s;
        }
    }
    __syncthreads();
    if (tid < 256) {
        float s = rowsum[tid] + rowsum[256 + tid] + rowsum[512 + tid] + rowsum[768 + tid];
        partial[(size_t)cbx * B + row0 + tid] = s;
    }
}

// ---------- kernel 5: out[b] += sum_cb partial[cb][b] ----------
__global__ __launch_bounds__(256) void k_final(const float* __restrict__ partial,
                                               float* __restrict__ out, int ncb, int B) {
    int b = blockIdx.x * 256 + threadIdx.x;
    float s = out[b];
    for (int c = 0; c < ncb; ++c) s += partial[(size_t)c * B + b];
    out[b] = s;
}

// ---------- launch ----------
extern "C" void kernel_launch(void* const* d_in, const int* in_sizes, int n_in,
                              void* d_out, int out_size, void* d_ws, size_t ws_size,
                              hipStream_t stream) {
    const float* x      = (const float*)d_in[0];  // [B,1024]
    const float* W      = (const float*)d_in[1];  // [1024,16]
    const float* bias   = (const float*)d_in[2];  // [16]
    const float* v_bias = (const float*)d_in[3];  // [1]
    const int*   perms  = (const int*)d_in[4];    // [G,1024]
    float* out = (float*)d_out;

    const int N  = 1024;
    const int B  = in_sizes[0] / N;   // 16384
    const int G  = in_sizes[4] / N;   // 256
    const int GF = G * 16;            // 4096
    const int NCB = GF / 256;         // 16 col blocks

    char* w = (char*)d_ws;
    unsigned short* xb = (unsigned short*)w;                           // B*N*2   = 32 MB
    unsigned short* bT = (unsigned short*)(w + (size_t)B * N * 2);     // GF*N*2  = 8 MB
    int* inv = (int*)(w + (size_t)B * N * 2 + (size_t)GF * N * 2);     // G*N*4   = 1 MB
    float* partial = (float*)(w + (size_t)B * N * 2 + (size_t)GF * N * 2
                              + (size_t)G * N * 4);                    // NCB*B*4 = 1 MB

    k_invert<<<G * N / 256, 256, 0, stream>>>(perms, inv);
    k_build_bt<<<GF, 256, 0, stream>>>(W, inv, bT);
    k_convert<<<B, 256, 0, stream>>>(x, v_bias, xb, out);
    k_gemm<<<dim3(NCB, B / 256), 512, 0, stream>>>(xb, bT, bias, partial, B);
    k_final<<<B / 256, 256, 0, stream>>>(partial, out, NCB, B);
}

// Round 4
// 196.040 us; speedup vs baseline: 1.9245x; 1.0033x over previous
//
#include <hip/hip_runtime.h>
#include <math.h>

typedef __bf16 bf16x8 __attribute__((ext_vector_type(8)));
typedef float f32x4 __attribute__((ext_vector_type(4)));

// ---------- helpers ----------

__device__ __forceinline__ unsigned short f2bf(float f) {
    unsigned int u = __float_as_uint(f);
    u += 0x7FFFu + ((u >> 16) & 1u);   // round-to-nearest-even
    return (unsigned short)(u >> 16);
}

// fast logcosh via HW v_exp/v_log (TRANS pipe). abs err ~1e-6/elem, budget 0.02.
__device__ __forceinline__ float logcosh_fast(float v) {
    float a = fabsf(v);
    float t = __expf(-2.0f * a);
    return a + (__logf(1.0f + t) - 0.6931471805599453f);
}

// DPP row_shr add; after shr 1,2,4,8 lane 15 of each 16-lane row holds row sum.
template <int CTRL>
__device__ __forceinline__ float dppadd(float x) {
    int y = __builtin_amdgcn_update_dpp(0, __float_as_int(x), CTRL, 0xf, 0xf, true);
    return x + __int_as_float(y);
}

__device__ __forceinline__ void gload_lds16(const void* g, void* l) {
    __builtin_amdgcn_global_load_lds(
        (__attribute__((address_space(1))) void*)(void*)g,
        (__attribute__((address_space(3))) void*)l, 16, 0, 0);
}

// ---------- kernel 1: invert permutations ----------
__global__ __launch_bounds__(256) void k_invert(const int* __restrict__ perms,
                                                int* __restrict__ inv) {
    int t = blockIdx.x * 256 + threadIdx.x;
    int g = t >> 10, n = t & 1023;
    inv[(g << 10) + perms[t]] = n;
}

// ---------- kernel 2: bT[j][k] = bf16(W[inv[g][k]][f]), j = g*16+f ----------
__global__ __launch_bounds__(256) void k_build_bt(const float* __restrict__ W,
                                                  const int* __restrict__ inv,
                                                  unsigned short* __restrict__ bT) {
    int j = blockIdx.x;
    int g = j >> 4, f = j & 15;
    const int* invg = inv + (g << 10);
    size_t rowbase = (size_t)j << 10;
#pragma unroll
    for (int i = 0; i < 4; ++i) {
        int k = (i << 8) + threadIdx.x;
        int n = invg[k];
        bT[rowbase + k] = f2bf(W[(n << 4) + f]);
    }
}

// ---------- kernel 3: x -> bf16, out[row] = v_bias * sum(x[row]) ----------
__global__ __launch_bounds__(256) void k_convert(const float* __restrict__ x,
                                                 const float* __restrict__ vb,
                                                 unsigned short* __restrict__ xb,
                                                 float* __restrict__ out) {
    int row = blockIdx.x, tid = threadIdx.x;
    size_t base = ((size_t)row << 10) + (tid << 2);
    float4 v = *reinterpret_cast<const float4*>(x + base);
    ushort4 h;
    h.x = f2bf(v.x); h.y = f2bf(v.y); h.z = f2bf(v.z); h.w = f2bf(v.w);
    *reinterpret_cast<ushort4*>(xb + base) = h;
    float s = v.x + v.y + v.z + v.w;
#pragma unroll
    for (int off = 32; off > 0; off >>= 1) s += __shfl_down(s, off);
    __shared__ float ls[4];
    if ((tid & 63) == 0) ls[tid >> 6] = s;
    __syncthreads();
    if (tid == 0) out[row] = vb[0] * (ls[0] + ls[1] + ls[2] + ls[3]);
}

// ---------- kernel 4: 256x256 GEMM, counted-wait pipeline + fused logcosh ----------
// 16 K-tiles of BK=64, double-buffered LDS, 2 barriers + 3 counted lgkm + 1 counted
// vmcnt per K-tile. Reads of buffer p all issue in phase 1 (quadrant-ordered);
// counted lgkmcnt overlaps MFMA with remaining reads. Stages into p deferred to
// phase 4 (after the all-reads-drained barrier) -> race-free by construction.

#define MFMA_QUAD(MH, NH)                                                        \
    _Pragma("unroll") for (int m_ = 0; m_ < 4; ++m_)                             \
    _Pragma("unroll") for (int n_ = 0; n_ < 2; ++n_)                             \
    _Pragma("unroll") for (int kk_ = 0; kk_ < 2; ++kk_)                          \
        acc[(MH) * 4 + m_][(NH) * 2 + n_] =                                      \
            __builtin_amdgcn_mfma_f32_16x16x32_bf16(                             \
                aF[(MH) * 4 + m_][kk_], bF[(NH) * 2 + n_][kk_],                  \
                acc[(MH) * 4 + m_][(NH) * 2 + n_], 0, 0, 0);

__global__ __launch_bounds__(512) void k_gemm(const unsigned short* __restrict__ xb,
                                              const unsigned short* __restrict__ bT,
                                              const float* __restrict__ bias,
                                              float* __restrict__ partial, int B) {
    __shared__ unsigned short As[2][256 * 64];
    __shared__ unsigned short Bs[2][256 * 64];

    const int tid = threadIdx.x;
    const int lane = tid & 63;
    const int wv = tid >> 6;           // 0..7
    const int wm = wv >> 2;            // 0..1  (M half)
    const int wn = wv & 3;             // 0..3  (N quarter)
    const int lr = lane & 15;
    const int lk = lane >> 4;

    // XCD-bijective swizzle (nwg = 1024, % 8 == 0)
    const int fid = blockIdx.y * gridDim.x + blockIdx.x;
    const int cpx = (gridDim.x * gridDim.y) >> 3;
    const int swz = (fid & 7) * cpx + (fid >> 3);
    const int cbx = swz & 15;          // col block (0..15)
    const int row0 = (swz >> 4) << 8;  // row block * 256
    const int j0 = cbx << 8;

    const unsigned short* xbase = xb + ((size_t)row0 << 10);
    const unsigned short* bbase = bT + ((size_t)j0 << 10);

    // stage one half-tile (128 rows x 64 cols bf16 = 16KB) = 2 gload_lds x 512 thr
    auto stage_half = [&](unsigned short* dst, const unsigned short* src, int h) {
#pragma unroll
        for (int j = 0; j < 2; ++j) {
            int c0 = (h * 128 + j * 64) * 8;       // base chunk of this instr
            int cc = c0 + tid;                     // this thread's 16B chunk
            int r = cc >> 3;                       // tile row 0..255
            int cs = (cc & 7) ^ (r & 7);           // pre-swizzled source octet
            gload_lds16(src + (((size_t)r) << 10) + (cs << 3),
                        dst + ((c0 + wv * 64) << 3));
        }
    };
    // stage sequence: s0=(t+1,B,h1)  s1=(t+2,A,h0)  s2=(t+2,A,h1)  s3=(t+2,B,h0)
    auto stage_s = [&](int t, int s) {
        int tt = (s == 0) ? t + 1 : t + 2;
        if (tt >= 16) return;
        int p = tt & 1;
        int kt = tt << 6;
        if (s == 0)      stage_half(Bs[p], bbase + kt, 1);
        else if (s == 1) stage_half(As[p], xbase + kt, 0);
        else if (s == 2) stage_half(As[p], xbase + kt, 1);
        else             stage_half(Bs[p], bbase + kt, 0);
    };

    f32x4 acc[8][4];
#pragma unroll
    for (int m = 0; m < 8; ++m)
#pragma unroll
        for (int n = 0; n < 4; ++n)
            acc[m][n] = {0.f, 0.f, 0.f, 0.f};

    // ---- prologue: tile0 complete (4 halves), tile1 A0,A1,B0 ----
    stage_half(As[0], xbase + 0, 0);
    stage_half(As[0], xbase + 0, 1);
    stage_half(Bs[0], bbase + 0, 0);
    stage_half(Bs[0], bbase + 0, 1);
    stage_half(As[1], xbase + 64, 0);
    stage_half(As[1], xbase + 64, 1);
    stage_half(Bs[1], bbase + 64, 0);
    asm volatile("s_waitcnt vmcnt(6)" ::: "memory");   // tile0 landed; 6 in flight
    __builtin_amdgcn_s_barrier();

    // ---- main loop ----
#pragma unroll 2
    for (int t = 0; t < 16; ++t) {
        const int p = t & 1;
        const unsigned short* Ap = As[p];
        const unsigned short* Bp = Bs[p];
        bf16x8 aF[8][2], bF[4][2];

        // ---- phase 1: stage s0 early; issue ALL 24 ds_reads quadrant-ordered
        stage_s(t, 0);
        __builtin_amdgcn_sched_barrier(0);
        // group 1 (12 reads): frags for quadrant (0,0) = aF[0..3], bF[0..1]
#pragma unroll
        for (int m = 0; m < 4; ++m) {
            int r = wm * 128 + m * 16 + lr;
#pragma unroll
            for (int kk = 0; kk < 2; ++kk) {
                int pos = ((kk << 2) + lk) ^ (r & 7);
                aF[m][kk] = *reinterpret_cast<const bf16x8*>(Ap + (r << 6) + (pos << 3));
            }
        }
#pragma unroll
        for (int n = 0; n < 2; ++n) {
            int rb = wn * 64 + n * 16 + lr;
#pragma unroll
            for (int kk = 0; kk < 2; ++kk) {
                int pos = ((kk << 2) + lk) ^ (rb & 7);
                bF[n][kk] = *reinterpret_cast<const bf16x8*>(Bp + (rb << 6) + (pos << 3));
            }
        }
        __builtin_amdgcn_sched_barrier(0);
        // group 2 (8 reads): aF[4..7] for quadrant (1,0)
#pragma unroll
        for (int m = 4; m < 8; ++m) {
            int r = wm * 128 + m * 16 + lr;
#pragma unroll
            for (int kk = 0; kk < 2; ++kk) {
                int pos = ((kk << 2) + lk) ^ (r & 7);
                aF[m][kk] = *reinterpret_cast<const bf16x8*>(Ap + (r << 6) + (pos << 3));
            }
        }
        __builtin_amdgcn_sched_barrier(0);
        // group 3 (4 reads): bF[2..3] for quadrant (0,1)
#pragma unroll
        for (int n = 2; n < 4; ++n) {
            int rb = wn * 64 + n * 16 + lr;
#pragma unroll
            for (int kk = 0; kk < 2; ++kk) {
                int pos = ((kk << 2) + lk) ^ (rb & 7);
                bF[n][kk] = *reinterpret_cast<const bf16x8*>(Bp + (rb << 6) + (pos << 3));
            }
        }
        __builtin_amdgcn_sched_barrier(0);
        // quadrant (0,0): its 12 reads are the oldest; 12 newer may remain
        asm volatile("s_waitcnt lgkmcnt(12)" ::: "memory");
        __builtin_amdgcn_sched_barrier(0);
        __builtin_amdgcn_s_setprio(1);
        MFMA_QUAD(0, 0)
        __builtin_amdgcn_s_setprio(0);
        __builtin_amdgcn_sched_barrier(0);

        // ---- phase 2: quadrant (1,0) after group-2 reads drain
        asm volatile("s_waitcnt lgkmcnt(4)" ::: "memory");
        __builtin_amdgcn_sched_barrier(0);
        __builtin_amdgcn_s_setprio(1);
        MFMA_QUAD(1, 0)
        __builtin_amdgcn_s_setprio(0);
        __builtin_amdgcn_sched_barrier(0);

        // ---- phase 3: quadrant (0,1) after all reads drain
        asm volatile("s_waitcnt lgkmcnt(0)" ::: "memory");
        __builtin_amdgcn_sched_barrier(0);
        __builtin_amdgcn_s_setprio(1);
        MFMA_QUAD(0, 1)
        __builtin_amdgcn_s_setprio(0);
        __builtin_amdgcn_s_barrier();   // all waves' reads of buffer p drained

        // ---- phase 4: stages into buffer p (tile t+2) now safe; MFMA (1,1)
        __builtin_amdgcn_sched_barrier(0);
        stage_s(t, 1);
        stage_s(t, 2);
        stage_s(t, 3);
        __builtin_amdgcn_sched_barrier(0);
        __builtin_amdgcn_s_setprio(1);
        MFMA_QUAD(1, 1)
        __builtin_amdgcn_s_setprio(0);
        if (t < 14) {
            asm volatile("s_waitcnt vmcnt(6)" ::: "memory");   // tile t+1 landed
        } else if (t == 14) {
            asm volatile("s_waitcnt vmcnt(0)" ::: "memory");
        }
        __builtin_amdgcn_s_barrier();   // tile t+1 ready for next window
    }

    // ---- epilogue: fast logcosh + DPP row-reduce; reuse As as scratch ----
    float* rowsum = (float*)&As[0][0];   // [4][256]
    const float bv = bias[lr];           // C col % 16 == lane&15
#pragma unroll
    for (int m = 0; m < 8; ++m) {
#pragma unroll
        for (int r = 0; r < 4; ++r) {
            float s = 0.f;
#pragma unroll
            for (int n = 0; n < 4; ++n) s += logcosh_fast(acc[m][n][r] + bv);
            s = dppadd<0x111>(s);
            s = dppadd<0x112>(s);
            s = dppadd<0x114>(s);
            s = dppadd<0x118>(s);
            if (lr == 15)
                rowsum[wn * 256 + wm * 128 + m * 16 + lk * 4 + r] = s;
        }
    }
    __syncthreads();
    if (tid < 256) {
        float s = rowsum[tid] + rowsum[256 + tid] + rowsum[512 + tid] + rowsum[768 + tid];
        partial[(size_t)cbx * B + row0 + tid] = s;
    }
}

// ---------- kernel 5: out[b] += sum_cb partial[cb][b] ----------
__global__ __launch_bounds__(256) void k_final(const float* __restrict__ partial,
                                               float* __restrict__ out, int ncb, int B) {
    int b = blockIdx.x * 256 + threadIdx.x;
    float s = out[b];
    for (int c = 0; c < ncb; ++c) s += partial[(size_t)c * B + b];
    out[b] = s;
}

// ---------- launch ----------
extern "C" void kernel_launch(void* const* d_in, const int* in_sizes, int n_in,
                              void* d_out, int out_size, void* d_ws, size_t ws_size,
                              hipStream_t stream) {
    const float* x      = (const float*)d_in[0];  // [B,1024]
    const float* W      = (const float*)d_in[1];  // [1024,16]
    const float* bias   = (const float*)d_in[2];  // [16]
    const float* v_bias = (const float*)d_in[3];  // [1]
    const int*   perms  = (const int*)d_in[4];    // [G,1024]
    float* out = (float*)d_out;

    const int N  = 1024;
    const int B  = in_sizes[0] / N;   // 16384
    const int G  = in_sizes[4] / N;   // 256
    const int GF = G * 16;            // 4096
    const int NCB = GF / 256;         // 16 col blocks

    char* w = (char*)d_ws;
    unsigned short* xb = (unsigned short*)w;                           // B*N*2   = 32 MB
    unsigned short* bT = (unsigned short*)(w + (size_t)B * N * 2);     // GF*N*2  = 8 MB
    int* inv = (int*)(w + (size_t)B * N * 2 + (size_t)GF * N * 2);     // G*N*4   = 1 MB
    float* partial = (float*)(w + (size_t)B * N * 2 + (size_t)GF * N * 2
                              + (size_t)G * N * 4);                    // NCB*B*4 = 1 MB

    k_invert<<<G * N / 256, 256, 0, stream>>>(perms, inv);
    k_build_bt<<<GF, 256, 0, stream>>>(W, inv, bT);
    k_convert<<<B, 256, 0, stream>>>(x, v_bias, xb, out);
    k_gemm<<<dim3(NCB, B / 256), 512, 0, stream>>>(xb, bT, bias, partial, B);
    k_final<<<B / 256, 256, 0, stream>>>(partial, out, NCB, B);
}